// Round 2
// baseline (119.988 us; speedup 1.0000x reference)
//
#include <hip/hip_runtime.h>
#include <hip/hip_bf16.h>
#include <float.h>

#define VOCAB 128256
#define HID 256
#define NLANG 100
#define BATCH 64
#define SEQ 2048

#define LTILES 7                       // 7*16 = 112 >= 100 langs
#define KK 8                           // 256 / 32
#define BLOCK 512
#define WAVES 8
#define TOK_PER_BLOCK 256
#define ITERS (TOK_PER_BLOCK / (WAVES * 16))   // 2
#define CHUNKS (SEQ / TOK_PER_BLOCK)   // 8
#define PAD_L (LTILES * 16)            // 112

typedef __attribute__((ext_vector_type(8))) short bf16x8;  // 8 bf16 in 4 VGPRs
typedef __attribute__((ext_vector_type(4))) float f32x4;

// fp32 -> bf16 bits, round-to-nearest-even
__device__ inline short f2bf(float f) {
    unsigned u = __builtin_bit_cast(unsigned, f);
    u = (u + 0x7fffu + ((u >> 16) & 1u)) >> 16;
    return (short)u;
}

// Kernel 1: per (batch, seq-chunk) block: gather -> bf16 MFMA vs proj_w ->
// post-scale by token weight -> max over the chunk's 256 tokens.
// 8 waves/block; each wave handles 2 tiles of 16 tokens.
__global__ __launch_bounds__(BLOCK, 4) void ld_score_kernel(
    const int* __restrict__ token_ids,
    const float* __restrict__ embeddings,
    const float* __restrict__ token_weights,
    const float* __restrict__ proj_w,
    float* __restrict__ partial)
{
    // proj_w in LDS in B-fragment layout (lane-linear, conflict-free):
    // bs[lt][kk][lane] = 8 bf16: B[k = kk*32 + (lane>>4)*8 + j][col = lt*16 + (lane&15)]
    __shared__ short bs[LTILES][KK][64][8];     // 57344 B
    __shared__ float wmax[WAVES][LTILES][16];   // 3584 B

    const int t = threadIdx.x;
    const int lane = t & 63;
    const int w = t >> 6;

    // ---- stage proj_w -> LDS; 3584 frags / 512 thr = 7 each
    #pragma unroll
    for (int i = 0; i < 7; ++i) {
        int f   = i * BLOCK + t;
        int fl  = f & 63;
        int fkk = (f >> 6) & 7;
        int flt = f >> 9;
        int row  = flt * 16 + (fl & 15);
        int colb = fkk * 32 + (fl >> 4) * 8;
        bf16x8 v;
        if (row < NLANG) {
            const float* p = proj_w + row * HID + colb;
            float4 p0 = *reinterpret_cast<const float4*>(p);
            float4 p1 = *reinterpret_cast<const float4*>(p + 4);
            v[0] = f2bf(p0.x); v[1] = f2bf(p0.y); v[2] = f2bf(p0.z); v[3] = f2bf(p0.w);
            v[4] = f2bf(p1.x); v[5] = f2bf(p1.y); v[6] = f2bf(p1.z); v[7] = f2bf(p1.w);
        } else {
            v = (bf16x8)0;
        }
        *reinterpret_cast<bf16x8*>(&bs[flt][fkk][fl][0]) = v;
    }
    __syncthreads();

    const int b     = blockIdx.x / CHUNKS;
    const int chunk = blockIdx.x % CHUNKS;

    const int tt = lane & 15;   // token within 16-tile (A-fragment row)
    const int kg = lane >> 4;   // k-group

    float rmax[LTILES];
    #pragma unroll
    for (int lt = 0; lt < LTILES; ++lt) rmax[lt] = -FLT_MAX;

    // Prefetch token ids + weights for both iterations (off critical path).
    int   tid[ITERS];
    float wtv[ITERS];
    #pragma unroll
    for (int it = 0; it < ITERS; ++it) {
        int s = chunk * TOK_PER_BLOCK + (it * WAVES + w) * 16;
        tid[it] = token_ids[b * SEQ + s + tt];
    }
    #pragma unroll
    for (int it = 0; it < ITERS; ++it) wtv[it] = token_weights[tid[it]];

    #pragma unroll
    for (int it = 0; it < ITERS; ++it) {
        const float* erow = embeddings + (size_t)tid[it] * HID + kg * 8;

        // A fragments: lane holds emb[token tt][kk*32 + kg*8 .. +8], bf16 (unscaled)
        bf16x8 a[KK];
        #pragma unroll
        for (int kk = 0; kk < KK; ++kk) {
            float4 p0 = *reinterpret_cast<const float4*>(erow + kk * 32);
            float4 p1 = *reinterpret_cast<const float4*>(erow + kk * 32 + 4);
            bf16x8 av;
            av[0] = f2bf(p0.x); av[1] = f2bf(p0.y);
            av[2] = f2bf(p0.z); av[3] = f2bf(p0.w);
            av[4] = f2bf(p1.x); av[5] = f2bf(p1.y);
            av[6] = f2bf(p1.z); av[7] = f2bf(p1.w);
            a[kk] = av;
        }

        // Per-D-row token weights: D row (token) = (lane>>4)*4 + reg.
        float w0 = __shfl(wtv[it], kg * 4 + 0, 64);
        float w1 = __shfl(wtv[it], kg * 4 + 1, 64);
        float w2 = __shfl(wtv[it], kg * 4 + 2, 64);
        float w3 = __shfl(wtv[it], kg * 4 + 3, 64);

        #pragma unroll
        for (int lt = 0; lt < LTILES; ++lt) {
            f32x4 acc = {0.f, 0.f, 0.f, 0.f};
            #pragma unroll
            for (int kk = 0; kk < KK; ++kk) {
                bf16x8 bv = *reinterpret_cast<const bf16x8*>(&bs[lt][kk][lane][0]);
                acc = __builtin_amdgcn_mfma_f32_16x16x32_bf16(a[kk], bv, acc, 0, 0, 0);
            }
            // D: col(lang)=lane&15, row(token)=(lane>>4)*4+reg. Scale per-token, then max.
            float m = fmaxf(fmaxf(acc[0] * w0, acc[1] * w1),
                            fmaxf(acc[2] * w2, acc[3] * w3));
            rmax[lt] = fmaxf(rmax[lt], m);
        }
    }

    // max across the 4 k-groups (lanes sharing lane&15) -> max over all 16 token rows
    #pragma unroll
    for (int lt = 0; lt < LTILES; ++lt) {
        float m = rmax[lt];
        m = fmaxf(m, __shfl_xor(m, 16, 64));
        m = fmaxf(m, __shfl_xor(m, 32, 64));
        rmax[lt] = m;
    }

    if (kg == 0) {
        #pragma unroll
        for (int lt = 0; lt < LTILES; ++lt) wmax[w][lt][tt] = rmax[lt];
    }
    __syncthreads();

    if (t < PAD_L) {
        int lt = t >> 4, li = t & 15;
        float m = -FLT_MAX;
        #pragma unroll
        for (int ww = 0; ww < WAVES; ++ww)
            m = fmaxf(m, wmax[ww][lt][li]);
        partial[(b * CHUNKS + chunk) * PAD_L + t] = m;
    }
}

// Kernel 2: reduce chunks, add bias (max(x)+b == max(x+b), b is per-lang).
__global__ void ld_reduce_kernel(const float* __restrict__ partial,
                                 const float* __restrict__ proj_b,
                                 float* __restrict__ out)
{
    const int b = blockIdx.x;
    const int l = threadIdx.x;
    if (l >= NLANG) return;
    float m = -FLT_MAX;
    #pragma unroll
    for (int c = 0; c < CHUNKS; ++c)
        m = fmaxf(m, partial[(b * CHUNKS + c) * PAD_L + l]);
    out[b * NLANG + l] = m + proj_b[l];
}

extern "C" void kernel_launch(void* const* d_in, const int* in_sizes, int n_in,
                              void* d_out, int out_size, void* d_ws, size_t ws_size,
                              hipStream_t stream) {
    const int*   token_ids     = (const int*)d_in[0];
    const float* embeddings    = (const float*)d_in[1];
    const float* token_weights = (const float*)d_in[2];
    const float* proj_w        = (const float*)d_in[3];
    const float* proj_b        = (const float*)d_in[4];
    float* out = (float*)d_out;
    float* partial = (float*)d_ws;   // BATCH*CHUNKS*PAD_L*4 = 229376 B

    ld_score_kernel<<<BATCH * CHUNKS, BLOCK, 0, stream>>>(
        token_ids, embeddings, token_weights, proj_w, partial);
    ld_reduce_kernel<<<BATCH, 128, 0, stream>>>(partial, proj_b, out);
}

// Round 3
// 70.270 us; speedup vs baseline: 1.7075x; 1.7075x over previous
//
#include <hip/hip_runtime.h>
#include <hip/hip_bf16.h>
#include <float.h>

#define VOCAB 128256
#define HID 256
#define NLANG 100
#define BATCH 64
#define SEQ 2048

#define LTILES 7                       // 7*16 = 112 >= 100 langs
#define KK 8                           // 256 / 32
#define BLOCK 256
#define WAVES 4
#define TOK_PER_BLOCK 256
#define ITERS (TOK_PER_BLOCK / (WAVES * 16))   // 4
#define CHUNKS (SEQ / TOK_PER_BLOCK)   // 8
#define PAD_L (LTILES * 16)            // 112

typedef __attribute__((ext_vector_type(8))) short bf16x8;  // 8 bf16 in 4 VGPRs
typedef __attribute__((ext_vector_type(4))) float f32x4;

// fp32 -> bf16 bits, round-to-nearest-even
__device__ inline short f2bf(float f) {
    unsigned u = __builtin_bit_cast(unsigned, f);
    u = (u + 0x7fffu + ((u >> 16) & 1u)) >> 16;
    return (short)u;
}

// Kernel 1: per (batch, seq-chunk) block: gather -> bf16 MFMA vs proj_w ->
// post-scale by token weight -> max over the chunk's 256 tokens.
// 4 waves/block, 4 token-tiles per wave, 2-deep software-pipelined gather.
__global__ __launch_bounds__(BLOCK, 2) void ld_score_kernel(
    const int* __restrict__ token_ids,
    const float* __restrict__ embeddings,
    const float* __restrict__ token_weights,
    const float* __restrict__ proj_w,
    float* __restrict__ partial)
{
    // proj_w in LDS in B-fragment layout (lane-linear, conflict-free):
    // bs[lt][kk][lane] = 8 bf16: B[k = kk*32 + (lane>>4)*8 + j][col = lt*16 + (lane&15)]
    __shared__ short bs[LTILES][KK][64][8];     // 57344 B
    __shared__ float wmax[WAVES][LTILES][16];   // 1792 B

    const int t = threadIdx.x;
    const int lane = t & 63;
    const int w = t >> 6;

    // ---- stage proj_w -> LDS; 3584 frags / 256 thr = 14 each
    #pragma unroll
    for (int i = 0; i < 14; ++i) {
        int f   = i * BLOCK + t;
        int fl  = f & 63;
        int fkk = (f >> 6) & 7;
        int flt = f >> 9;
        int row  = flt * 16 + (fl & 15);
        int colb = fkk * 32 + (fl >> 4) * 8;
        bf16x8 v;
        if (row < NLANG) {
            const float* p = proj_w + row * HID + colb;
            float4 p0 = *reinterpret_cast<const float4*>(p);
            float4 p1 = *reinterpret_cast<const float4*>(p + 4);
            v[0] = f2bf(p0.x); v[1] = f2bf(p0.y); v[2] = f2bf(p0.z); v[3] = f2bf(p0.w);
            v[4] = f2bf(p1.x); v[5] = f2bf(p1.y); v[6] = f2bf(p1.z); v[7] = f2bf(p1.w);
        } else {
            v = (bf16x8)0;
        }
        *reinterpret_cast<bf16x8*>(&bs[flt][fkk][fl][0]) = v;
    }
    __syncthreads();

    const int b     = blockIdx.x / CHUNKS;
    const int chunk = blockIdx.x % CHUNKS;

    const int tt = lane & 15;   // token within 16-tile (A-fragment row)
    const int kg = lane >> 4;   // k-group

    float rmax[LTILES];
    #pragma unroll
    for (int lt = 0; lt < LTILES; ++lt) rmax[lt] = -FLT_MAX;

    // Token ids + weights for all iterations, hoisted off the critical path.
    int   tids[ITERS];
    float wts[ITERS];
    #pragma unroll
    for (int it = 0; it < ITERS; ++it) {
        int s = chunk * TOK_PER_BLOCK + (it * WAVES + w) * 16;
        tids[it] = token_ids[b * SEQ + s + tt];
    }
    #pragma unroll
    for (int it = 0; it < ITERS; ++it) wts[it] = token_weights[tids[it]];

    // 2-deep software pipeline: raw f32 embedding data for iter it+1 is in
    // flight while iter it converts + MFMAs. 2*16 float4 = 128 VGPRs.
    float4 raw[2][2 * KK];

    {
        const float* e0 = embeddings + (size_t)tids[0] * HID + kg * 8;
        #pragma unroll
        for (int kk = 0; kk < KK; ++kk) {
            raw[0][2 * kk]     = *reinterpret_cast<const float4*>(e0 + kk * 32);
            raw[0][2 * kk + 1] = *reinterpret_cast<const float4*>(e0 + kk * 32 + 4);
        }
    }

    #pragma unroll
    for (int it = 0; it < ITERS; ++it) {
        const int cur = it & 1;
        const int nxt = cur ^ 1;

        // Issue next iteration's 16 loads before touching this iteration's data.
        if (it + 1 < ITERS) {
            const float* en = embeddings + (size_t)tids[it + 1] * HID + kg * 8;
            #pragma unroll
            for (int kk = 0; kk < KK; ++kk) {
                raw[nxt][2 * kk]     = *reinterpret_cast<const float4*>(en + kk * 32);
                raw[nxt][2 * kk + 1] = *reinterpret_cast<const float4*>(en + kk * 32 + 4);
            }
        }

        // Convert current raw data to bf16 A-fragments (unscaled).
        bf16x8 a[KK];
        #pragma unroll
        for (int kk = 0; kk < KK; ++kk) {
            float4 p0 = raw[cur][2 * kk];
            float4 p1 = raw[cur][2 * kk + 1];
            bf16x8 av;
            av[0] = f2bf(p0.x); av[1] = f2bf(p0.y);
            av[2] = f2bf(p0.z); av[3] = f2bf(p0.w);
            av[4] = f2bf(p1.x); av[5] = f2bf(p1.y);
            av[6] = f2bf(p1.z); av[7] = f2bf(p1.w);
            a[kk] = av;
        }

        // Per-D-row token weights: D row (token) = (lane>>4)*4 + reg.
        float w0 = __shfl(wts[it], kg * 4 + 0, 64);
        float w1 = __shfl(wts[it], kg * 4 + 1, 64);
        float w2 = __shfl(wts[it], kg * 4 + 2, 64);
        float w3 = __shfl(wts[it], kg * 4 + 3, 64);

        #pragma unroll
        for (int lt = 0; lt < LTILES; ++lt) {
            f32x4 acc = {0.f, 0.f, 0.f, 0.f};
            #pragma unroll
            for (int kk = 0; kk < KK; ++kk) {
                bf16x8 bv = *reinterpret_cast<const bf16x8*>(&bs[lt][kk][lane][0]);
                acc = __builtin_amdgcn_mfma_f32_16x16x32_bf16(a[kk], bv, acc, 0, 0, 0);
            }
            // D: col(lang)=lane&15, row(token)=(lane>>4)*4+reg. Scale per-token, then max.
            float m = fmaxf(fmaxf(acc[0] * w0, acc[1] * w1),
                            fmaxf(acc[2] * w2, acc[3] * w3));
            rmax[lt] = fmaxf(rmax[lt], m);
        }
    }

    // max across the 4 k-groups (lanes sharing lane&15) -> max over all 16 token rows
    #pragma unroll
    for (int lt = 0; lt < LTILES; ++lt) {
        float m = rmax[lt];
        m = fmaxf(m, __shfl_xor(m, 16, 64));
        m = fmaxf(m, __shfl_xor(m, 32, 64));
        rmax[lt] = m;
    }

    if (kg == 0) {
        #pragma unroll
        for (int lt = 0; lt < LTILES; ++lt) wmax[w][lt][tt] = rmax[lt];
    }
    __syncthreads();

    if (t < PAD_L) {
        int lt = t >> 4, li = t & 15;
        float m = -FLT_MAX;
        #pragma unroll
        for (int ww = 0; ww < WAVES; ++ww)
            m = fmaxf(m, wmax[ww][lt][li]);
        partial[(b * CHUNKS + chunk) * PAD_L + t] = m;
    }
}

// Kernel 2: reduce chunks, add bias (max(x)+b == max(x+b), b is per-lang).
__global__ void ld_reduce_kernel(const float* __restrict__ partial,
                                 const float* __restrict__ proj_b,
                                 float* __restrict__ out)
{
    const int b = blockIdx.x;
    const int l = threadIdx.x;
    if (l >= NLANG) return;
    float m = -FLT_MAX;
    #pragma unroll
    for (int c = 0; c < CHUNKS; ++c)
        m = fmaxf(m, partial[(b * CHUNKS + c) * PAD_L + l]);
    out[b * NLANG + l] = m + proj_b[l];
}

extern "C" void kernel_launch(void* const* d_in, const int* in_sizes, int n_in,
                              void* d_out, int out_size, void* d_ws, size_t ws_size,
                              hipStream_t stream) {
    const int*   token_ids     = (const int*)d_in[0];
    const float* embeddings    = (const float*)d_in[1];
    const float* token_weights = (const float*)d_in[2];
    const float* proj_w        = (const float*)d_in[3];
    const float* proj_b        = (const float*)d_in[4];
    float* out = (float*)d_out;
    float* partial = (float*)d_ws;   // BATCH*CHUNKS*PAD_L*4 = 229376 B

    ld_score_kernel<<<BATCH * CHUNKS, BLOCK, 0, stream>>>(
        token_ids, embeddings, token_weights, proj_w, partial);
    ld_reduce_kernel<<<BATCH, 128, 0, stream>>>(partial, proj_b, out);
}

// Round 5
// 33.611 us; speedup vs baseline: 3.5699x; 2.0907x over previous
//
#include <hip/hip_runtime.h>
#include <hip/hip_bf16.h>
#include <float.h>

#define VOCAB 128256
#define HID 256
#define NLANG 100
#define BATCH 64
#define SEQ 2048

#define CHUNKS 8
#define TOKB 256                 // tokens per block
#define NTILE (TOKB / 16)        // 16 token-tiles of 16
#define BLOCK 256
#define PADL 128                 // padded lang count (8 lt * 16)
#define APITCH 260               // f32 words per token row in LDS (1040 B: 16B-aligned, bank-balanced)

typedef __attribute__((ext_vector_type(8))) short bf16x8;
typedef __attribute__((ext_vector_type(4))) float f32x4;
typedef __attribute__((ext_vector_type(4))) unsigned int u32x4;

// fp32 -> bf16 bits, round-to-nearest-even
__device__ inline short f2bf(float f) {
    unsigned u = __builtin_bit_cast(unsigned, f);
    u = (u + 0x7fffu + ((u >> 16) & 1u)) >> 16;
    return (short)u;
}

// HW packed cvt: dst.lo = bf16(lo), dst.hi = bf16(hi), RNE
__device__ inline unsigned int cvt_pk_bf16(float lo, float hi) {
    unsigned int r;
    asm("v_cvt_pk_bf16_f32 %0, %1, %2" : "=v"(r) : "v"(lo), "v"(hi));
    return r;
}

// async global->LDS, 16 B per lane; dest = wave-uniform base + lane*16
__device__ inline void gload16(const void* g, void* l) {
    __builtin_amdgcn_global_load_lds(
        (const __attribute__((address_space(1))) void*)g,
        (__attribute__((address_space(3))) void*)l, 16, 0, 0);
}

// Kernel 0: proj_w (f32) -> bf16 B-fragments in ws.
// bfrag[lt][kk][lane][8]: B[k = kk*32 + (lane>>4)*8 + j][lang = lt*16 + (lane&15)]
__global__ void ld_cvtb_kernel(const float* __restrict__ proj_w,
                               short* __restrict__ bfrag) {
    int f = blockIdx.x * 256 + threadIdx.x;      // 0..4095
    int lane = f & 63, kk = (f >> 6) & 7, lt = f >> 9;
    int row  = lt * 16 + (lane & 15);
    int colb = kk * 32 + (lane >> 4) * 8;
    bf16x8 v;
    if (row < NLANG) {
        const float* p = proj_w + row * HID + colb;
        float4 p0 = *reinterpret_cast<const float4*>(p);
        float4 p1 = *reinterpret_cast<const float4*>(p + 4);
        v[0] = f2bf(p0.x); v[1] = f2bf(p0.y); v[2] = f2bf(p0.z); v[3] = f2bf(p0.w);
        v[4] = f2bf(p1.x); v[5] = f2bf(p1.y); v[6] = f2bf(p1.z); v[7] = f2bf(p1.w);
    } else {
        v = (bf16x8)0;
    }
    *reinterpret_cast<bf16x8*>(&bfrag[(size_t)f * 8]) = v;
}

// Kernel 1: per (batch, chunk) block. Token rows DMA'd global->LDS
// (global_load_lds, 4-buffer rotation, 2-tile prefetch depth, counted vmcnt),
// B-fragments live in registers (2 lang-tiles per wave).
// Deadlock audit: uniform control flow; each wave waits only its OWN tile-j
// DMAs (vmcnt(8) of 12 outstanding) then s_barrier publishes all rows; buffer
// (j+2)&3 was last read at tile j-2, which completed before barrier j-1.
__global__ __launch_bounds__(BLOCK, 2) void ld_score_kernel(
    const int* __restrict__ token_ids,
    const float* __restrict__ embeddings,
    const float* __restrict__ token_weights,
    const short* __restrict__ bfrag,
    float* __restrict__ partial)
{
    __shared__ float abuf[4][16][APITCH];   // 66560 B
    __shared__ int   ids_lds[TOKB];         // 1 KB
    __shared__ float wts_lds[TOKB];         // 1 KB

    const int t = threadIdx.x;
    const int lane = t & 63;
    const int wu = __builtin_amdgcn_readfirstlane(t >> 6);
    const int b = blockIdx.x / CHUNKS, chunk = blockIdx.x % CHUNKS;
    const int s0 = chunk * TOKB;

    // ---- B fragments -> registers (wave wu owns lang-tiles 2wu, 2wu+1)
    const int lt0 = 2 * wu, lt1 = 2 * wu + 1;
    bf16x8 b0[8], b1[8];
    #pragma unroll
    for (int kk = 0; kk < 8; ++kk) {
        b0[kk] = *reinterpret_cast<const bf16x8*>(&bfrag[((size_t)(lt0 * 8 + kk) * 64 + lane) * 8]);
        b1[kk] = *reinterpret_cast<const bf16x8*>(&bfrag[((size_t)(lt1 * 8 + kk) * 64 + lane) * 8]);
    }

    // ---- stage token ids + weights (keeps vector-global loads OUT of the main loop)
    {
        int id = token_ids[b * SEQ + s0 + t];
        ids_lds[t] = id;
        wts_lds[t] = token_weights[id];
    }
    __syncthreads();   // full drain: B regs + id/wt stores all resolved

    const int tt = lane & 15;   // token within tile (A row, D col-group)
    const int kg = lane >> 4;   // k-group

    // Issue one tile's 16 token-row DMAs; wave wu issues tokens 4wu..4wu+3.
    auto issue = [&](int j) {
        #pragma unroll
        for (int i = 0; i < 4; ++i) {
            int tki = 4 * wu + i;
            int tid = ids_lds[j * 16 + tki];
            const float* g = embeddings + (size_t)tid * HID + lane * 4;
            gload16(g, &abuf[j & 3][tki][0]);
        }
    };

    float rmax0 = -FLT_MAX, rmax1 = -FLT_MAX;

    issue(0);
    issue(1);

    #pragma unroll
    for (int j = 0; j < NTILE; ++j) {
        if (j + 2 < NTILE) issue(j + 2);
        // wait for tile j's DMAs (mine); barrier covers the other waves' shares.
        if (j < NTILE - 2)       asm volatile("s_waitcnt vmcnt(8)" ::: "memory");
        else if (j == NTILE - 2) asm volatile("s_waitcnt vmcnt(4)" ::: "memory");
        else                     asm volatile("s_waitcnt vmcnt(0)" ::: "memory");
        __builtin_amdgcn_s_barrier();

        // per-D-row token weights: D row (token) = kg*4 + r
        float4 wv = *reinterpret_cast<const float4*>(&wts_lds[j * 16 + kg * 4]);

        f32x4 acc0 = {0.f, 0.f, 0.f, 0.f};
        f32x4 acc1 = {0.f, 0.f, 0.f, 0.f};
        #pragma unroll
        for (int kk = 0; kk < 8; ++kk) {
            const float* ap = &abuf[j & 3][tt][kg * 8 + kk * 32];
            float4 p0 = *reinterpret_cast<const float4*>(ap);
            float4 p1 = *reinterpret_cast<const float4*>(ap + 4);
            u32x4 u;
            u[0] = cvt_pk_bf16(p0.x, p0.y); u[1] = cvt_pk_bf16(p0.z, p0.w);
            u[2] = cvt_pk_bf16(p1.x, p1.y); u[3] = cvt_pk_bf16(p1.z, p1.w);
            bf16x8 av = __builtin_bit_cast(bf16x8, u);
            acc0 = __builtin_amdgcn_mfma_f32_16x16x32_bf16(av, b0[kk], acc0, 0, 0, 0);
            acc1 = __builtin_amdgcn_mfma_f32_16x16x32_bf16(av, b1[kk], acc1, 0, 0, 0);
        }
        // D: col(lang)=lane&15, row(token)=kg*4+reg. Scale per-token, then max.
        float m0 = fmaxf(fmaxf(acc0[0] * wv.x, acc0[1] * wv.y),
                         fmaxf(acc0[2] * wv.z, acc0[3] * wv.w));
        float m1 = fmaxf(fmaxf(acc1[0] * wv.x, acc1[1] * wv.y),
                         fmaxf(acc1[2] * wv.z, acc1[3] * wv.w));
        rmax0 = fmaxf(rmax0, m0);
        rmax1 = fmaxf(rmax1, m1);
    }

    // max across the 4 k-groups -> max over all 16 token rows per tile
    rmax0 = fmaxf(rmax0, __shfl_xor(rmax0, 16, 64));
    rmax0 = fmaxf(rmax0, __shfl_xor(rmax0, 32, 64));
    rmax1 = fmaxf(rmax1, __shfl_xor(rmax1, 16, 64));
    rmax1 = fmaxf(rmax1, __shfl_xor(rmax1, 32, 64));

    if (lane < 16) {
        partial[(size_t)blockIdx.x * PADL + lt0 * 16 + lane] = rmax0;
        partial[(size_t)blockIdx.x * PADL + lt1 * 16 + lane] = rmax1;
    }
}

// Kernel 2: reduce chunks, add bias (max(x)+b == max(x+b), b is per-lang).
__global__ void ld_reduce_kernel(const float* __restrict__ partial,
                                 const float* __restrict__ proj_b,
                                 float* __restrict__ out)
{
    const int b = blockIdx.x;
    const int l = threadIdx.x;
    if (l >= NLANG) return;
    float m = -FLT_MAX;
    #pragma unroll
    for (int c = 0; c < CHUNKS; ++c)
        m = fmaxf(m, partial[(size_t)(b * CHUNKS + c) * PADL + l]);
    out[b * NLANG + l] = m + proj_b[l];
}

extern "C" void kernel_launch(void* const* d_in, const int* in_sizes, int n_in,
                              void* d_out, int out_size, void* d_ws, size_t ws_size,
                              hipStream_t stream) {
    const int*   token_ids     = (const int*)d_in[0];
    const float* embeddings    = (const float*)d_in[1];
    const float* token_weights = (const float*)d_in[2];
    const float* proj_w        = (const float*)d_in[3];
    const float* proj_b        = (const float*)d_in[4];
    float* out = (float*)d_out;

    float* partial = (float*)d_ws;                           // 512*128*4 = 262144 B
    short* bfrag   = (short*)((char*)d_ws + 262144);         // 8*8*64*8*2 = 65536 B

    ld_cvtb_kernel<<<16, 256, 0, stream>>>(proj_w, bfrag);
    ld_score_kernel<<<BATCH * CHUNKS, BLOCK, 0, stream>>>(
        token_ids, embeddings, token_weights, bfrag, partial);
    ld_reduce_kernel<<<BATCH, 128, 0, stream>>>(partial, proj_b, out);
}